// Round 3
// baseline (132.805 us; speedup 1.0000x reference)
//
#include <hip/hip_runtime.h>
#include <hip/hip_cooperative_groups.h>
#include <math.h>

namespace cg = cooperative_groups;

// Problem constants
#define BB 8
#define NN 1024
#define TT 512
#define KK 9
#define HH 32

#define NCHUNK 32          // n-chunks (grid.x)
#define NPER   (NN/NCHUNK) // 32 n per chunk

__constant__ float c_epos[KK][3] = {
    { 0.30f,  0.25f, 0.00f},
    {-0.30f,  0.25f, 0.00f},
    {-0.05f, -0.40f, 0.00f},
    { 0.03f,  0.05f, 0.20f},
    { 0.00f,  0.05f, 0.22f},
    {-0.04f,  0.01f, 0.21f},
    {-0.08f, -0.02f, 0.18f},
    {-0.14f, -0.02f, 0.13f},
    {-0.20f, -0.02f, 0.07f},
};

// mode 0: phase A + grid.sync + finalize (cooperative, 1 node)
// mode 1: phase A only (fallback kernel 1)
// mode 2: finalize only (fallback kernel 2, grid (32,2))
__global__ __launch_bounds__(512) void ecg_kernel(
    const float* __restrict__ pos,   // (B,N,3)
    const float* __restrict__ dd,    // (B,N,3)
    const float* __restrict__ amp,   // (B,N)
    const float* __restrict__ env,   // (B,N,T)
    const float* __restrict__ eoff,  // (B,K,3)
    const float* __restrict__ W1,    // (H,7)
    const float* __restrict__ pb1,   // (H)
    const float* __restrict__ W2,    // (1,H)
    const float* __restrict__ pb2,   // (1)
    float* __restrict__ partial,     // (NCHUNK,B,K,T) in ws
    float* __restrict__ out,         // v_leads (B,12,T) ++ V_elec (B,K,T)
    int mode)
{
    const int tid = threadIdx.x;

    __shared__ float sW1[HH * 7];
    __shared__ float sb1[HH];
    __shared__ float sW2[HH];
    __shared__ float sb2;
    __shared__ float sE[KK][3];
    __shared__ float sA[NPER][12];      // 9 coeffs padded to 12 -> float4 broadcast
    __shared__ float sV[8][KK][64];     // finalize partial sums
    __shared__ float sR[KK][64];        // clipped V

    if (mode != 2) {
        // ---------------- Phase A: per-(chunk,b) partial GEMV ----------------
        const int chunk = blockIdx.x;
        const int b     = blockIdx.y;
        const int n0    = chunk * NPER;

        if (tid < HH * 7) sW1[tid] = W1[tid];
        if (tid < HH)     { sb1[tid] = pb1[tid]; sW2[tid] = W2[tid]; }
        if (tid < KK * 3) sE[tid / 3][tid % 3] = c_epos[tid / 3][tid % 3] + eoff[b * KK * 3 + tid];
        if (tid == 0)     sb2 = pb2[0];
        __syncthreads();

        if (tid < NPER * KK) {          // 288 MLP evals, one per thread
            const int k  = tid % KK;
            const int nl = tid / KK;
            const int bn = b * NN + n0 + nl;

            const float px = pos[bn * 3 + 0];
            const float py = pos[bn * 3 + 1];
            const float pz = pos[bn * 3 + 2];

            const float rx = sE[k][0] - px, ry = sE[k][1] - py, rz = sE[k][2] - pz;
            const float r2 = rx * rx + ry * ry + rz * rz;
            const float d0 = r2 + 0.04f;
            const float denom = d0 * sqrtf(d0);

            const float rdist = fmaxf(sqrtf(r2), 1e-6f);
            const float rinv  = 1.0f / rdist;
            float feat[7];
            feat[0] = px; feat[1] = py; feat[2] = pz;
            feat[3] = rx * rinv; feat[4] = ry * rinv; feat[5] = rz * rinv;
            feat[6] = rdist;

            float raw = sb2;
            #pragma unroll
            for (int j = 0; j < HH; ++j) {
                float s = sb1[j];
                #pragma unroll
                for (int f = 0; f < 7; ++f) s += sW1[j * 7 + f] * feat[f];
                const float g = 0.5f * s * (1.0f + erff(s * 0.70710678118654752f));
                raw += sW2[j] * g;
            }
            const float corr = 1.0f + 0.5f * tanhf(raw);

            const float ddx = dd[bn * 3 + 0], ddy = dd[bn * 3 + 1], ddz = dd[bn * 3 + 2];
            const float dot = ddx * rx + ddy * ry + ddz * rz;

            sA[nl][k] = amp[bn] * dot * corr / denom;
        }
        __syncthreads();

        // each thread owns one t
        const int t = tid;
        float acc[KK];
        #pragma unroll
        for (int k = 0; k < KK; ++k) acc[k] = 0.0f;

        const float* envp = env + ((size_t)(b * NN + n0)) * TT + t;
        const float4* s4 = (const float4*)sA;
        #pragma unroll 8
        for (int nl = 0; nl < NPER; ++nl) {
            const float ev = envp[(size_t)nl * TT];
            const float4 a0 = s4[nl * 3 + 0];
            const float4 a1 = s4[nl * 3 + 1];
            const float  a8 = sA[nl][8];
            acc[0] += a0.x * ev; acc[1] += a0.y * ev; acc[2] += a0.z * ev;
            acc[3] += a0.w * ev; acc[4] += a1.x * ev; acc[5] += a1.y * ev;
            acc[6] += a1.z * ev; acc[7] += a1.w * ev; acc[8] += a8   * ev;
        }

        float* pp = partial + (((size_t)chunk * BB + b) * KK) * TT + t;
        #pragma unroll
        for (int k = 0; k < KK; ++k) pp[(size_t)k * TT] = acc[k];
    }

    if (mode == 0) {
        __threadfence();                 // release partials (cross-XCD L2)
        cg::this_grid().sync();
        __threadfence();                 // acquire
        __syncthreads();
    }

    if (mode != 1) {
        // ---------------- Phase B: reduce 32 chunks, clip, leads ----------------
        const int fb = blockIdx.y * 32 + blockIdx.x;   // mode0: 0..255, mode2: 0..63
        if (fb < 64) {
            const int b  = fb >> 3;     // 0..7
            const int tc = fb & 7;      // 0..7
            const int tl = tid & 63;
            const int cg8 = tid >> 6;   // 0..7
            const int t  = tc * 64 + tl;

            float s[KK];
            #pragma unroll
            for (int k = 0; k < KK; ++k) s[k] = 0.0f;

            for (int c = cg8; c < NCHUNK; c += 8) {
                const float* pp = partial + (((size_t)c * BB + b) * KK) * TT + t;
                #pragma unroll
                for (int k = 0; k < KK; ++k) s[k] += pp[(size_t)k * TT];
            }

            #pragma unroll
            for (int k = 0; k < KK; ++k) sV[cg8][k][tl] = s[k];
            __syncthreads();

            for (int idx = tid; idx < KK * 64; idx += 512) {
                const int k   = idx >> 6;
                const int tl2 = idx & 63;
                float v = 0.0f;
                #pragma unroll
                for (int g = 0; g < 8; ++g) v += sV[g][k][tl2];
                sR[k][tl2] = fminf(fmaxf(v, -50.0f), 50.0f);
            }
            __syncthreads();

            if (tid < 64) {
                float V[KK];
                #pragma unroll
                for (int k = 0; k < KK; ++k) V[k] = sR[k][tid];

                float* vleads = out;                        // (B,12,T)
                float* velec  = out + (size_t)BB * 12 * TT; // (B,K,T)

                #pragma unroll
                for (int k = 0; k < KK; ++k)
                    velec[((size_t)b * KK + k) * TT + t] = V[k];

                const float RA = V[0], LA = V[1], LL = V[2];
                const float WCT = (RA + LA + LL) * (1.0f / 3.0f);

                float L[12];
                L[0] = LA - RA;
                L[1] = LL - RA;
                L[2] = LL - LA;
                L[3] = RA - 0.5f * (LA + LL);
                L[4] = LA - 0.5f * (RA + LL);
                L[5] = LL - 0.5f * (RA + LA);
                L[6]  = V[3] - WCT;
                L[7]  = V[4] - WCT;
                L[8]  = V[5] - WCT;
                L[9]  = V[6] - WCT;
                L[10] = V[7] - WCT;
                L[11] = V[8] - WCT;

                #pragma unroll
                for (int l = 0; l < 12; ++l)
                    vleads[((size_t)b * 12 + l) * TT + t] = L[l];
            }
        }
    }
}

extern "C" void kernel_launch(void* const* d_in, const int* in_sizes, int n_in,
                              void* d_out, int out_size, void* d_ws, size_t ws_size,
                              hipStream_t stream) {
    const float* pos  = (const float*)d_in[0];
    const float* dd   = (const float*)d_in[1];
    const float* amp  = (const float*)d_in[2];
    const float* env  = (const float*)d_in[3];
    const float* eoff = (const float*)d_in[4];
    const float* W1   = (const float*)d_in[5];
    const float* b1   = (const float*)d_in[6];
    const float* W2   = (const float*)d_in[7];
    const float* b2   = (const float*)d_in[8];
    float* out = (float*)d_out;

    float* partial = (float*)d_ws;   // (NCHUNK,B,K,T) floats = 4.7 MB

    int mode0 = 0;
    void* args[] = {
        (void*)&pos, (void*)&dd, (void*)&amp, (void*)&env, (void*)&eoff,
        (void*)&W1, (void*)&b1, (void*)&W2, (void*)&b2,
        (void*)&partial, (void*)&out, (void*)&mode0
    };
    hipError_t e = hipLaunchCooperativeKernel((void*)ecg_kernel,
                                              dim3(NCHUNK, BB), dim3(512),
                                              args, 0, stream);
    if (e != hipSuccess) {
        // Fallback: same kernel as two ordinary launches (kernel-boundary
        // flush provides the cross-XCD visibility the grid.sync gave us).
        (void)hipGetLastError();
        ecg_kernel<<<dim3(NCHUNK, BB), 512, 0, stream>>>(
            pos, dd, amp, env, eoff, W1, b1, W2, b2, partial, out, 1);
        ecg_kernel<<<dim3(32, 2), 512, 0, stream>>>(
            pos, dd, amp, env, eoff, W1, b1, W2, b2, partial, out, 2);
    }
}

// Round 4
// 19.571 us; speedup vs baseline: 6.7859x; 6.7859x over previous
//
#include <hip/hip_runtime.h>
#include <hip/hip_bf16.h>
#include <math.h>

// Problem constants
#define BB 8
#define NN 1024
#define TT 512
#define KK 9
#define HH 32

#define NCHUNK 64          // n-chunks (grid.x of phase A)
#define NPER   (NN/NCHUNK) // 16 n per chunk

__constant__ float c_epos[KK][3] = {
    { 0.30f,  0.25f, 0.00f},
    {-0.30f,  0.25f, 0.00f},
    {-0.05f, -0.40f, 0.00f},
    { 0.03f,  0.05f, 0.20f},
    { 0.00f,  0.05f, 0.22f},
    {-0.04f,  0.01f, 0.21f},
    {-0.08f, -0.02f, 0.18f},
    {-0.14f, -0.02f, 0.13f},
    {-0.20f, -0.02f, 0.07f},
};

// Phase A: block (chunk, b) computes A[b, n0:n0+16, :] via MLP into LDS,
// then partial[c,b,k,0:512] += over its 16 n. Each thread owns 2 t (float2).
__global__ __launch_bounds__(256) void fused_kernel(
    const float* __restrict__ pos,   // (B,N,3)
    const float* __restrict__ dd,    // (B,N,3)
    const float* __restrict__ amp,   // (B,N)
    const float* __restrict__ env,   // (B,N,T)
    const float* __restrict__ eoff,  // (B,K,3)
    const float* __restrict__ W1,    // (H,7)
    const float* __restrict__ pb1,   // (H)
    const float* __restrict__ W2,    // (1,H)
    const float* __restrict__ pb2,   // (1)
    float* __restrict__ partial)     // (NCHUNK,B,K,T)
{
    const int tid   = threadIdx.x;
    const int chunk = blockIdx.x;
    const int b     = blockIdx.y;
    const int n0    = chunk * NPER;

    __shared__ float sW1[HH * 7];
    __shared__ float sb1[HH];
    __shared__ float sW2[HH];
    __shared__ float sb2;
    __shared__ float sE[KK][3];
    __shared__ float sA[NPER][12];   // 9 coeffs padded to 12 -> float4 reads

    if (tid < HH * 7) sW1[tid] = W1[tid];
    if (tid < HH)     { sb1[tid] = pb1[tid]; sW2[tid] = W2[tid]; }
    if (tid < KK * 3) sE[tid / 3][tid % 3] = c_epos[tid / 3][tid % 3] + eoff[b * KK * 3 + tid];
    if (tid == 0)     sb2 = pb2[0];
    __syncthreads();

    if (tid < NPER * KK) {           // 144 MLP evals, one per thread
        const int k  = tid % KK;
        const int nl = tid / KK;
        const int bn = b * NN + n0 + nl;

        const float px = pos[bn * 3 + 0];
        const float py = pos[bn * 3 + 1];
        const float pz = pos[bn * 3 + 2];

        const float rx = sE[k][0] - px, ry = sE[k][1] - py, rz = sE[k][2] - pz;
        const float r2 = rx * rx + ry * ry + rz * rz;
        const float d0 = r2 + 0.04f;
        const float denom = d0 * sqrtf(d0);

        const float rdist = fmaxf(sqrtf(r2), 1e-6f);
        const float rinv  = 1.0f / rdist;
        float feat[7];
        feat[0] = px; feat[1] = py; feat[2] = pz;
        feat[3] = rx * rinv; feat[4] = ry * rinv; feat[5] = rz * rinv;
        feat[6] = rdist;

        float raw = sb2;
        #pragma unroll
        for (int j = 0; j < HH; ++j) {
            float s = sb1[j];
            #pragma unroll
            for (int f = 0; f < 7; ++f) s += sW1[j * 7 + f] * feat[f];
            const float g = 0.5f * s * (1.0f + erff(s * 0.70710678118654752f));
            raw += sW2[j] * g;
        }
        const float corr = 1.0f + 0.5f * tanhf(raw);

        const float ddx = dd[bn * 3 + 0], ddy = dd[bn * 3 + 1], ddz = dd[bn * 3 + 2];
        const float dot = ddx * rx + ddy * ry + ddz * rz;

        sA[nl][k] = amp[bn] * dot * corr / denom;
    }
    __syncthreads();

    // Main loop: thread owns t = {2*tid, 2*tid+1}; 16 rows, fully unrolled.
    float2 acc[KK];
    #pragma unroll
    for (int k = 0; k < KK; ++k) { acc[k].x = 0.0f; acc[k].y = 0.0f; }

    const float2* envp = (const float2*)(env + ((size_t)(b * NN + n0)) * TT) + tid;
    const float4* s4 = (const float4*)sA;
    #pragma unroll
    for (int nl = 0; nl < NPER; ++nl) {
        const float2 ev = envp[(size_t)nl * (TT / 2)];
        const float4 a0 = s4[nl * 3 + 0];
        const float4 a1 = s4[nl * 3 + 1];
        const float  a8 = sA[nl][8];
        acc[0].x += a0.x * ev.x; acc[0].y += a0.x * ev.y;
        acc[1].x += a0.y * ev.x; acc[1].y += a0.y * ev.y;
        acc[2].x += a0.z * ev.x; acc[2].y += a0.z * ev.y;
        acc[3].x += a0.w * ev.x; acc[3].y += a0.w * ev.y;
        acc[4].x += a1.x * ev.x; acc[4].y += a1.x * ev.y;
        acc[5].x += a1.y * ev.x; acc[5].y += a1.y * ev.y;
        acc[6].x += a1.z * ev.x; acc[6].y += a1.z * ev.y;
        acc[7].x += a1.w * ev.x; acc[7].y += a1.w * ev.y;
        acc[8].x += a8   * ev.x; acc[8].y += a8   * ev.y;
    }

    float2* pp = (float2*)(partial + (((size_t)chunk * BB + b) * KK) * TT) + tid;
    #pragma unroll
    for (int k = 0; k < KK; ++k) pp[(size_t)k * (TT / 2)] = acc[k];
}

// Finalize: V = clip(sum_c partial, -50, 50); emit leads + V_electrodes.
// grid (16, 8): 32 t per block, 8 c-groups.
__global__ __launch_bounds__(256) void finalize_kernel(
    const float* __restrict__ partial,  // (NCHUNK,B,K,T)
    float* __restrict__ out)            // v_leads (B,12,T) then V_elec (B,K,T)
{
    const int tid = threadIdx.x;
    const int tl  = tid & 31;
    const int cg  = tid >> 5;       // 0..7
    const int tc  = blockIdx.x;     // 0..15
    const int b   = blockIdx.y;
    const int t   = tc * 32 + tl;

    float s[KK];
    #pragma unroll
    for (int k = 0; k < KK; ++k) s[k] = 0.0f;

    #pragma unroll
    for (int ci = 0; ci < NCHUNK / 8; ++ci) {
        const int c = cg + ci * 8;
        const float* pp = partial + (((size_t)c * BB + b) * KK) * TT + t;
        #pragma unroll
        for (int k = 0; k < KK; ++k) s[k] += pp[(size_t)k * TT];
    }

    __shared__ float sV[8][KK][32];
    __shared__ float sR[KK][32];
    #pragma unroll
    for (int k = 0; k < KK; ++k) sV[cg][k][tl] = s[k];
    __syncthreads();

    for (int idx = tid; idx < KK * 32; idx += 256) {
        const int k   = idx >> 5;
        const int tl2 = idx & 31;
        float v = 0.0f;
        #pragma unroll
        for (int g = 0; g < 8; ++g) v += sV[g][k][tl2];
        sR[k][tl2] = fminf(fmaxf(v, -50.0f), 50.0f);
    }
    __syncthreads();

    if (tid < 32) {
        float V[KK];
        #pragma unroll
        for (int k = 0; k < KK; ++k) V[k] = sR[k][tid];

        float* vleads = out;                        // (B,12,T)
        float* velec  = out + (size_t)BB * 12 * TT; // (B,K,T)

        #pragma unroll
        for (int k = 0; k < KK; ++k)
            velec[((size_t)b * KK + k) * TT + t] = V[k];

        const float RA = V[0], LA = V[1], LL = V[2];
        const float WCT = (RA + LA + LL) * (1.0f / 3.0f);

        float L[12];
        L[0] = LA - RA;
        L[1] = LL - RA;
        L[2] = LL - LA;
        L[3] = RA - 0.5f * (LA + LL);
        L[4] = LA - 0.5f * (RA + LL);
        L[5] = LL - 0.5f * (RA + LA);
        L[6]  = V[3] - WCT;
        L[7]  = V[4] - WCT;
        L[8]  = V[5] - WCT;
        L[9]  = V[6] - WCT;
        L[10] = V[7] - WCT;
        L[11] = V[8] - WCT;

        #pragma unroll
        for (int l = 0; l < 12; ++l)
            vleads[((size_t)b * 12 + l) * TT + t] = L[l];
    }
}

extern "C" void kernel_launch(void* const* d_in, const int* in_sizes, int n_in,
                              void* d_out, int out_size, void* d_ws, size_t ws_size,
                              hipStream_t stream) {
    const float* pos  = (const float*)d_in[0];
    const float* dd   = (const float*)d_in[1];
    const float* amp  = (const float*)d_in[2];
    const float* env  = (const float*)d_in[3];
    const float* eoff = (const float*)d_in[4];
    const float* W1   = (const float*)d_in[5];
    const float* b1   = (const float*)d_in[6];
    const float* W2   = (const float*)d_in[7];
    const float* b2   = (const float*)d_in[8];
    float* out = (float*)d_out;

    float* partial = (float*)d_ws;   // (NCHUNK,B,K,T) floats = 9.4 MB

    {
        dim3 grid(NCHUNK, BB);           // 64 x 8 = 512 blocks
        fused_kernel<<<grid, 256, 0, stream>>>(
            pos, dd, amp, env, eoff, W1, b1, W2, b2, partial);
    }
    {
        dim3 grid(16, BB);               // 128 blocks
        finalize_kernel<<<grid, 256, 0, stream>>>(partial, out);
    }
}